// Round 2
// baseline (1139.311 us; speedup 1.0000x reference)
//
#include <hip/hip_runtime.h>
#include <math.h>

#define TPB 512        // 8 waves: wave w owns row-tile (w + t*8)
#define E 16           // elements per block
#define VSTR 264       // [e][k] stride for vector-activation LDS buffers (f16)
#define PLANE (E * VSTR)
#define SSTR 392       // scat stride
#define OSTR 136       // souts stride
#define SLOPE_VN 0.2f
#define SLOPE_SCA 0.01f
#define EPS_VN 1e-6f

using hfrag = __attribute__((ext_vector_type(8))) _Float16;
using h4    = __attribute__((ext_vector_type(4))) _Float16;
using ffrag = __attribute__((ext_vector_type(4))) float;

__device__ __forceinline__ ffrag mfma(hfrag a, hfrag b, ffrag c) {
  return __builtin_amdgcn_mfma_f32_16x16x32_f16(a, b, c, 0, 0, 0);
}

// ---- f16 weight pointers (into d_ws) ----
struct WB {
  const _Float16 *g1_Wvh,*g1_Ws,*g1_Wvo,*g1_Wg,*g1_Wd;
  const _Float16 *g2_Wvh,*g2_Ws,*g2_Wvo,*g2_Wg;
  const _Float16 *a1_Wvh,*a1_Ws,*a1_Wvo,*a1_Wg,*a1_Wd;
  const _Float16 *a2_Wvh,*a2_Ws,*a2_Wvo,*a2_Wg,*a2_Wd;
  const _Float16 *f_Wvh;
  const float *g1_bg,*g2_bg,*a1_bg,*a2_bg,*f_Ws;
};

// ---- weight f32->f16 conversion pre-pass ----
struct CvtJobs { const float* src[20]; _Float16* dst[20]; int n[20]; };

__global__ void cvt_kernel(CvtJobs J) {
  const int j = blockIdx.y;
  const float* __restrict__ s = J.src[j];
  _Float16* __restrict__ d = J.dst[j];
  const int n = J.n[j];
  for (int i = blockIdx.x * blockDim.x + threadIdx.x; i < n;
       i += gridDim.x * blockDim.x)
    d[i] = (_Float16)s[i];
}

// ---- GEMM helpers ----
// Vector GEMM: acc[t][c] += W[O][C] * v_c, tiles = wave + 8*t.
template<int TT, int KS>
__device__ __forceinline__ void gemmV(const _Float16* __restrict__ W, int C,
                                      const _Float16* vb, ffrag acc[TT][3]) {
  const int m = threadIdx.x & 15;
  const int q = (threadIdx.x >> 4) & 3;
  const int w = threadIdx.x >> 6;
  #pragma unroll
  for (int ks = 0; ks < KS; ++ks) {
    const int k = ks * 32 + q * 8;
    hfrag b0 = *(const hfrag*)(vb + 0 * PLANE + m * VSTR + k);
    hfrag b1 = *(const hfrag*)(vb + 1 * PLANE + m * VSTR + k);
    hfrag b2 = *(const hfrag*)(vb + 2 * PLANE + m * VSTR + k);
    #pragma unroll
    for (int t = 0; t < TT; ++t) {
      const int row = (w + t * 8) * 16 + m;
      hfrag a = *(const hfrag*)(W + (size_t)row * C + k);
      acc[t][0] = mfma(a, b0, acc[t][0]);
      acc[t][1] = mfma(a, b1, acc[t][1]);
      acc[t][2] = mfma(a, b2, acc[t][2]);
    }
  }
}

// Scalar GEMM: acc[t] += W[O][C] * s
template<int TT, int KS>
__device__ __forceinline__ void gemmS(const _Float16* __restrict__ W, int C,
                                      const _Float16* sb, int sstr, ffrag acc[TT]) {
  const int m = threadIdx.x & 15;
  const int q = (threadIdx.x >> 4) & 3;
  const int w = threadIdx.x >> 6;
  #pragma unroll
  for (int ks = 0; ks < KS; ++ks) {
    const int k = ks * 32 + q * 8;
    hfrag b = *(const hfrag*)(sb + m * sstr + k);
    #pragma unroll
    for (int t = 0; t < TT; ++t) {
      const int row = (w + t * 8) * 16 + m;
      hfrag a = *(const hfrag*)(W + (size_t)row * C + k);
      acc[t] = mfma(a, b, acc[t]);
    }
  }
}

// Store a C/D fragment into an [e][k] LDS buffer (4 consecutive k = rows).
__device__ __forceinline__ void stCD(_Float16* buf, int stride, int tile, ffrag v) {
  const int e = threadIdx.x & 15;
  const int q = (threadIdx.x >> 4) & 3;
  h4 p;
  p[0] = (_Float16)v[0]; p[1] = (_Float16)v[1];
  p[2] = (_Float16)v[2]; p[3] = (_Float16)v[3];
  *(h4*)(buf + e * stride + tile * 16 + q * 4) = p;
}

__device__ __forceinline__ float sigm(float x) { return 1.f / (1.f + expf(-x)); }

__global__ __launch_bounds__(TPB, 6) void pe_kernel(
    const float* __restrict__ h_sca, const float* __restrict__ h_vec,
    const float* __restrict__ pos_compose, const float* __restrict__ pos,
    WB W, const int* __restrict__ idx_focal, float* __restrict__ out, int F) {
  // Single vector buffer: contents progress v_in -> vh -> v_new -> v_final
  // within each layer; every transition is barrier-separated.
  __shared__ _Float16 sv [3 * PLANE];     // [comp][e][k]
  __shared__ _Float16 scat[E * SSTR];     // [vnorm | s | inner] per element
  __shared__ _Float16 souts[E * OSTR];    // raw out_s
  __shared__ float srel[E * 3];

  const int t = threadIdx.x;
  const int wv = t >> 6;          // 0..7
  const int q = (t >> 4) & 3;
  const int el = t >> 5;          // gather: element handled by 32 threads
  const int c5 = t & 31;
  const int eg = blockIdx.x * E + el;

  // ======== gather (f32 -> f16 LDS, float4 loads, h4 stores) ========
  {
    const int idx = (eg < F) ? idx_focal[eg] : 0;
    if (c5 < 16) {
      // h_vec row = 64 cols x 3 comps; thread u=c5 handles cols 4u..4u+3
      const float4* __restrict__ vsrc = (const float4*)(h_vec + (size_t)idx * 192);
      const float4 va = vsrc[3 * c5 + 0];
      const float4 vb = vsrc[3 * c5 + 1];
      const float4 vc = vsrc[3 * c5 + 2];
      const float f[12] = {va.x, va.y, va.z, va.w, vb.x, vb.y, vb.z, vb.w,
                           vc.x, vc.y, vc.z, vc.w};
      #pragma unroll
      for (int comp = 0; comp < 3; ++comp) {
        h4 p;
        p[0] = (_Float16)f[0 + comp]; p[1] = (_Float16)f[3 + comp];
        p[2] = (_Float16)f[6 + comp]; p[3] = (_Float16)f[9 + comp];
        *(h4*)(sv + comp * PLANE + el * VSTR + 4 * c5) = p;
      }
      if (c5 < 3 && eg < F)
        srel[el * 3 + c5] = pos[(size_t)eg * 3 + c5] - pos_compose[(size_t)idx * 3 + c5];
    } else {
      // h_sca row = 256 floats; thread u handles cols 16u..16u+15
      const int u = c5 - 16;
      const float4* __restrict__ ssrc = (const float4*)(h_sca + (size_t)idx * 256);
      #pragma unroll
      for (int i2 = 0; i2 < 4; ++i2) {
        const float4 vv = ssrc[4 * u + i2];
        h4 p;
        p[0] = (_Float16)vv.x; p[1] = (_Float16)vv.y;
        p[2] = (_Float16)vv.z; p[3] = (_Float16)vv.w;
        *(h4*)(scat + el * SSTR + 128 + 16 * u + 4 * i2) = p;
      }
    }
  }
  __syncthreads();

  ffrag zero = {0.f, 0.f, 0.f, 0.f};

  // ================= g1: perceptron (C=64 -> H=128 -> O=128) =================
  {
    ffrag vh[1][3];
    for (int c = 0; c < 3; ++c) vh[0][c] = zero;
    gemmV<1, 2>(W.g1_Wvh, 64, sv, vh);          // reads sv = v_in
    __syncthreads();                            // sv reads done
    {
      for (int c = 0; c < 3; ++c) stCD(sv + c * PLANE, VSTR, wv, vh[0][c]); // vh -> sv
      ffrag n;
      #pragma unroll
      for (int r = 0; r < 4; ++r)
        n[r] = sqrtf(vh[0][0][r]*vh[0][0][r] + vh[0][1][r]*vh[0][1][r] + vh[0][2][r]*vh[0][2][r]);
      stCD(scat, SSTR, wv, n);                  // vnorm -> scat[0:128]
    }
    __syncthreads();                            // vh + vnorm visible

    ffrag so[1]; so[0] = zero;
    ffrag ov[1][3];
    for (int c = 0; c < 3; ++c) ov[0][c] = zero;
    gemmS<1, 12>(W.g1_Ws, 384, scat, SSTR, so); // reads scat (vnorm|s_in)
    gemmV<1, 4>(W.g1_Wvo, 128, sv, ov);         // reads vh
    __syncthreads();                            // scat + sv reads done
    {
      stCD(souts, OSTR, wv, so[0]);             // raw out_s
      ffrag l;
      for (int r = 0; r < 4; ++r) { float x = so[0][r]; l[r] = x >= 0.f ? x : SLOPE_SCA * x; }
      stCD(scat + 128, SSTR, wv, l);            // s for g2 at [128:256]
    }
    __syncthreads();                            // souts visible

    ffrag g[1]; g[0] = zero;
    gemmS<1, 4>(W.g1_Wg, 128, souts, OSTR, g);
    {
      const float4 b = *(const float4*)(W.g1_bg + wv * 16 + q * 4);
      const float bb[4] = {b.x, b.y, b.z, b.w};
      #pragma unroll
      for (int r = 0; r < 4; ++r) {
        float gg = sigm(g[0][r] + bb[r]);
        ov[0][0][r] *= gg; ov[0][1][r] *= gg; ov[0][2][r] *= gg;
      }
      for (int c = 0; c < 3; ++c) stCD(sv + c * PLANE, VSTR, wv, ov[0][c]); // v_new -> sv
    }
    __syncthreads();                            // v_new visible

    ffrag d[1][3];
    for (int c = 0; c < 3; ++c) d[0][c] = zero;
    gemmV<1, 4>(W.g1_Wd, 128, sv, d);           // reads v_new
    __syncthreads();                            // v_new reads done
    {
      #pragma unroll
      for (int r = 0; r < 4; ++r) {
        float x0 = ov[0][0][r], x1 = ov[0][1][r], x2 = ov[0][2][r];
        float d0 = d[0][0][r],  d1 = d[0][1][r],  d2 = d[0][2][r];
        float dot = x0*d0 + x1*d1 + x2*d2;
        float kk = dot / (d0*d0 + d1*d1 + d2*d2 + EPS_VN);
        if (dot < 0.f) {
          ov[0][0][r] = SLOPE_VN*x0 + (1.f-SLOPE_VN)*(x0 - kk*d0);
          ov[0][1][r] = SLOPE_VN*x1 + (1.f-SLOPE_VN)*(x1 - kk*d1);
          ov[0][2][r] = SLOPE_VN*x2 + (1.f-SLOPE_VN)*(x2 - kk*d2);
        }
      }
      for (int c = 0; c < 3; ++c) stCD(sv + c * PLANE, VSTR, wv, ov[0][c]); // v_final
    }
    __syncthreads();
  }

  // ================= g2: linear (128 -> 128) =================
  {
    ffrag vh[1][3];
    for (int c = 0; c < 3; ++c) vh[0][c] = zero;
    gemmV<1, 4>(W.g2_Wvh, 128, sv, vh);
    __syncthreads();
    {
      for (int c = 0; c < 3; ++c) stCD(sv + c * PLANE, VSTR, wv, vh[0][c]);
      ffrag n;
      for (int r = 0; r < 4; ++r)
        n[r] = sqrtf(vh[0][0][r]*vh[0][0][r] + vh[0][1][r]*vh[0][1][r] + vh[0][2][r]*vh[0][2][r]);
      stCD(scat, SSTR, wv, n);
    }
    __syncthreads();

    ffrag so[1]; so[0] = zero;
    ffrag ov[1][3];
    for (int c = 0; c < 3; ++c) ov[0][c] = zero;
    gemmS<1, 8>(W.g2_Ws, 256, scat, SSTR, so);
    gemmV<1, 4>(W.g2_Wvo, 128, sv, ov);
    __syncthreads();
    {
      stCD(souts, OSTR, wv, so[0]);
      stCD(scat + 256, SSTR, wv, so[0]);        // s for a1 at [256:384], no act
    }
    __syncthreads();

    ffrag g[1]; g[0] = zero;
    gemmS<1, 4>(W.g2_Wg, 128, souts, OSTR, g);
    {
      const float4 b = *(const float4*)(W.g2_bg + wv * 16 + q * 4);
      const float bb[4] = {b.x, b.y, b.z, b.w};
      for (int r = 0; r < 4; ++r) {
        float gg = sigm(g[0][r] + bb[r]);
        ov[0][0][r] *= gg; ov[0][1][r] *= gg; ov[0][2][r] *= gg;
      }
      for (int c = 0; c < 3; ++c) stCD(sv + c * PLANE, VSTR, wv, ov[0][c]);
    }
    __syncthreads();
  }

  // ================= a1: perceptron (128 -> H=256 -> O=256) =================
  {
    ffrag vh[2][3];
    #pragma unroll
    for (int i = 0; i < 2; ++i) for (int c = 0; c < 3; ++c) vh[i][c] = zero;
    gemmV<2, 4>(W.a1_Wvh, 128, sv, vh);
    __syncthreads();
    #pragma unroll
    for (int i = 0; i < 2; ++i) {
      const int tile = wv + i * 8;
      for (int c = 0; c < 3; ++c) stCD(sv + c * PLANE, VSTR, tile, vh[i][c]);
      ffrag n;
      for (int r = 0; r < 4; ++r)
        n[r] = sqrtf(vh[i][0][r]*vh[i][0][r] + vh[i][1][r]*vh[i][1][r] + vh[i][2][r]*vh[i][2][r]);
      stCD(scat, SSTR, tile, n);                // vnorm -> scat[0:256]
    }
    __syncthreads();

    ffrag so[1]; so[0] = zero;
    ffrag ov[2][3];
    #pragma unroll
    for (int i = 0; i < 2; ++i) for (int c = 0; c < 3; ++c) ov[i][c] = zero;
    gemmS<1, 12>(W.a1_Ws, 384, scat, SSTR, so);
    gemmV<2, 8>(W.a1_Wvo, 256, sv, ov);         // reads vh (256-wide)
    __syncthreads();
    {
      stCD(souts, OSTR, wv, so[0]);
      ffrag l;
      for (int r = 0; r < 4; ++r) { float x = so[0][r]; l[r] = x >= 0.f ? x : SLOPE_SCA * x; }
      stCD(scat + 128, SSTR, wv, l);            // s1 for a2 at [128:256]
    }
    __syncthreads();

    ffrag g[2];
    #pragma unroll
    for (int i = 0; i < 2; ++i) g[i] = zero;
    gemmS<2, 4>(W.a1_Wg, 128, souts, OSTR, g);
    #pragma unroll
    for (int i = 0; i < 2; ++i) {
      const int tile = wv + i * 8;
      const float4 b = *(const float4*)(W.a1_bg + tile * 16 + q * 4);
      const float bb[4] = {b.x, b.y, b.z, b.w};
      for (int r = 0; r < 4; ++r) {
        float gg = sigm(g[i][r] + bb[r]);
        ov[i][0][r] *= gg; ov[i][1][r] *= gg; ov[i][2][r] *= gg;
      }
      for (int c = 0; c < 3; ++c) stCD(sv + c * PLANE, VSTR, tile, ov[i][c]); // v_new
    }
    __syncthreads();

    ffrag d[2][3];
    #pragma unroll
    for (int i = 0; i < 2; ++i) for (int c = 0; c < 3; ++c) d[i][c] = zero;
    gemmV<2, 8>(W.a1_Wd, 256, sv, d);
    __syncthreads();
    #pragma unroll
    for (int i = 0; i < 2; ++i) {
      for (int r = 0; r < 4; ++r) {
        float x0 = ov[i][0][r], x1 = ov[i][1][r], x2 = ov[i][2][r];
        float d0 = d[i][0][r],  d1 = d[i][1][r],  d2 = d[i][2][r];
        float dot = x0*d0 + x1*d1 + x2*d2;
        float kk = dot / (d0*d0 + d1*d1 + d2*d2 + EPS_VN);
        if (dot < 0.f) {
          ov[i][0][r] = SLOPE_VN*x0 + (1.f-SLOPE_VN)*(x0 - kk*d0);
          ov[i][1][r] = SLOPE_VN*x1 + (1.f-SLOPE_VN)*(x1 - kk*d1);
          ov[i][2][r] = SLOPE_VN*x2 + (1.f-SLOPE_VN)*(x2 - kk*d2);
        }
      }
      for (int c = 0; c < 3; ++c) stCD(sv + c * PLANE, VSTR, wv + i * 8, ov[i][c]); // v1
    }
    __syncthreads();
  }

  // ---- mid: inner[e][h] = <v1[128+h], relpos[e]> -> scat[256:384] ----
  {
    const float r0 = srel[el * 3 + 0], r1 = srel[el * 3 + 1], r2 = srel[el * 3 + 2];
    for (int h = c5; h < 128; h += 32) {
      float x0 = (float)sv[0 * PLANE + el * VSTR + 128 + h];
      float x1 = (float)sv[1 * PLANE + el * VSTR + 128 + h];
      float x2 = (float)sv[2 * PLANE + el * VSTR + 128 + h];
      scat[el * SSTR + 256 + h] = (_Float16)(x0 * r0 + x1 * r1 + x2 * r2);
    }
  }
  // no barrier: a2's Wvh gemm below only READS sv[0:128]; the barrier after it
  // covers mid's reads/writes before any LDS overwrite.

  // ================= a2: perceptron (v = v1[:,:128], s2 = [s1, inner]) =========
  {
    ffrag vh[1][3];
    for (int c = 0; c < 3; ++c) vh[0][c] = zero;
    gemmV<1, 4>(W.a2_Wvh, 128, sv, vh);
    __syncthreads();                            // sv reads + mid writes done
    {
      for (int c = 0; c < 3; ++c) stCD(sv + c * PLANE, VSTR, wv, vh[0][c]);
      ffrag n;
      for (int r = 0; r < 4; ++r)
        n[r] = sqrtf(vh[0][0][r]*vh[0][0][r] + vh[0][1][r]*vh[0][1][r] + vh[0][2][r]*vh[0][2][r]);
      stCD(scat, SSTR, wv, n);
    }
    __syncthreads();

    ffrag so[1]; so[0] = zero;
    ffrag ov[1][3];
    for (int c = 0; c < 3; ++c) ov[0][c] = zero;
    gemmS<1, 12>(W.a2_Ws, 384, scat, SSTR, so);
    gemmV<1, 4>(W.a2_Wvo, 128, sv, ov);
    __syncthreads();
    {
      stCD(souts, OSTR, wv, so[0]);
      ffrag l;
      for (int r = 0; r < 4; ++r) { float x = so[0][r]; l[r] = x >= 0.f ? x : SLOPE_SCA * x; }
      stCD(scat + 128, SSTR, wv, l);            // s_a2 for f at [128:256]
    }
    __syncthreads();

    ffrag g[1]; g[0] = zero;
    gemmS<1, 4>(W.a2_Wg, 128, souts, OSTR, g);
    {
      const float4 b = *(const float4*)(W.a2_bg + wv * 16 + q * 4);
      const float bb[4] = {b.x, b.y, b.z, b.w};
      for (int r = 0; r < 4; ++r) {
        float gg = sigm(g[0][r] + bb[r]);
        ov[0][0][r] *= gg; ov[0][1][r] *= gg; ov[0][2][r] *= gg;
      }
      for (int c = 0; c < 3; ++c) stCD(sv + c * PLANE, VSTR, wv, ov[0][c]);
    }
    __syncthreads();

    ffrag d[1][3];
    for (int c = 0; c < 3; ++c) d[0][c] = zero;
    gemmV<1, 4>(W.a2_Wd, 128, sv, d);
    __syncthreads();
    {
      for (int r = 0; r < 4; ++r) {
        float x0 = ov[0][0][r], x1 = ov[0][1][r], x2 = ov[0][2][r];
        float d0 = d[0][0][r],  d1 = d[0][1][r],  d2 = d[0][2][r];
        float dot = x0*d0 + x1*d1 + x2*d2;
        float kk = dot / (d0*d0 + d1*d1 + d2*d2 + EPS_VN);
        if (dot < 0.f) {
          ov[0][0][r] = SLOPE_VN*x0 + (1.f-SLOPE_VN)*(x0 - kk*d0);
          ov[0][1][r] = SLOPE_VN*x1 + (1.f-SLOPE_VN)*(x1 - kk*d1);
          ov[0][2][r] = SLOPE_VN*x2 + (1.f-SLOPE_VN)*(x2 - kk*d2);
        }
      }
      for (int c = 0; c < 3; ++c) stCD(sv + c * PLANE, VSTR, wv, ov[0][c]);
    }
    __syncthreads();
  }

  // ================= f: vnorm + final dot =================
  {
    ffrag vh[1][3];
    for (int c = 0; c < 3; ++c) vh[0][c] = zero;
    gemmV<1, 4>(W.f_Wvh, 128, sv, vh);
    {
      ffrag n;
      for (int r = 0; r < 4; ++r)
        n[r] = sqrtf(vh[0][0][r]*vh[0][0][r] + vh[0][1][r]*vh[0][1][r] + vh[0][2][r]*vh[0][2][r]);
      stCD(scat, SSTR, wv, n);
    }
    __syncthreads();

    float part = 0.f;
    for (int c = c5; c < 256; c += 32)
      part += (float)scat[el * SSTR + c] * W.f_Ws[c];
    part += __shfl_xor(part, 16, 32);
    part += __shfl_xor(part, 8, 32);
    part += __shfl_xor(part, 4, 32);
    part += __shfl_xor(part, 2, 32);
    part += __shfl_xor(part, 1, 32);
    if (c5 == 0 && eg < F) out[eg] = part;
  }
}

extern "C" void kernel_launch(void* const* d_in, const int* in_sizes, int n_in,
                              void* d_out, int out_size, void* d_ws, size_t ws_size,
                              hipStream_t stream) {
  const float* h_sca       = (const float*)d_in[0];
  const float* h_vec       = (const float*)d_in[1];
  const float* pos_compose = (const float*)d_in[2];
  const float* pos         = (const float*)d_in[3];
  const int* idx_focal     = (const int*)d_in[29];
  const int F = in_sizes[29];

  // weight conversion jobs: d_in index -> packed f16 in d_ws
  const int widx[20] = {4,5,6,7,9, 10,11,12,13, 15,16,17,18,20, 21,22,23,24,26, 27};
  CvtJobs J;
  _Float16* wsp = (_Float16*)d_ws;
  size_t off = 0;
  const _Float16* wptr[20];
  for (int j = 0; j < 20; ++j) {
    J.src[j] = (const float*)d_in[widx[j]];
    J.dst[j] = wsp + off;
    J.n[j]   = in_sizes[widx[j]];
    wptr[j]  = wsp + off;
    off += in_sizes[widx[j]];
  }
  cvt_kernel<<<dim3(32, 20), dim3(256), 0, stream>>>(J);

  WB W;
  W.g1_Wvh = wptr[0];  W.g1_Ws = wptr[1];  W.g1_Wvo = wptr[2];  W.g1_Wg = wptr[3];  W.g1_Wd = wptr[4];
  W.g2_Wvh = wptr[5];  W.g2_Ws = wptr[6];  W.g2_Wvo = wptr[7];  W.g2_Wg = wptr[8];
  W.a1_Wvh = wptr[9];  W.a1_Ws = wptr[10]; W.a1_Wvo = wptr[11]; W.a1_Wg = wptr[12]; W.a1_Wd = wptr[13];
  W.a2_Wvh = wptr[14]; W.a2_Ws = wptr[15]; W.a2_Wvo = wptr[16]; W.a2_Wg = wptr[17]; W.a2_Wd = wptr[18];
  W.f_Wvh  = wptr[19];
  W.g1_bg = (const float*)d_in[8];
  W.g2_bg = (const float*)d_in[14];
  W.a1_bg = (const float*)d_in[19];
  W.a2_bg = (const float*)d_in[25];
  W.f_Ws  = (const float*)d_in[28];

  const int blocks = (F + E - 1) / E;
  pe_kernel<<<dim3(blocks), dim3(TPB), 0, stream>>>(
      h_sca, h_vec, pos_compose, pos, W, idx_focal, (float*)d_out, F);
}

// Round 3
// 1118.101 us; speedup vs baseline: 1.0190x; 1.0190x over previous
//
#include <hip/hip_runtime.h>
#include <math.h>

#define TPB 512        // 8 waves: wave w owns row-tile (w + t*8)
#define E 16           // elements per block
#define VSTR 264       // [e][k] stride for vector-activation LDS buffers (f16)
#define PLANE (E * VSTR)
#define SSTR 392       // scat stride
#define OSTR 136       // souts stride
#define SLOPE_VN 0.2f
#define SLOPE_SCA 0.01f
#define EPS_VN 1e-6f

using hfrag = __attribute__((ext_vector_type(8))) _Float16;
using h4    = __attribute__((ext_vector_type(4))) _Float16;
using ffrag = __attribute__((ext_vector_type(4))) float;

__device__ __forceinline__ ffrag mfma(hfrag a, hfrag b, ffrag c) {
  return __builtin_amdgcn_mfma_f32_16x16x32_f16(a, b, c, 0, 0, 0);
}

// ---- f16 weight pointers (into d_ws) ----
struct WB {
  const _Float16 *g1_Wvh,*g1_Ws,*g1_Wvo,*g1_Wg,*g1_Wd;
  const _Float16 *g2_Wvh,*g2_Ws,*g2_Wvo,*g2_Wg;
  const _Float16 *a1_Wvh,*a1_Ws,*a1_Wvo,*a1_Wg,*a1_Wd;
  const _Float16 *a2_Wvh,*a2_Ws,*a2_Wvo,*a2_Wg,*a2_Wd;
  const _Float16 *f_Wvh;
  const float *g1_bg,*g2_bg,*a1_bg,*a2_bg,*f_Ws;
};

// ---- weight f32->f16 conversion pre-pass ----
struct CvtJobs { const float* src[20]; _Float16* dst[20]; int n[20]; };

__global__ void cvt_kernel(CvtJobs J) {
  const int j = blockIdx.y;
  const float* __restrict__ s = J.src[j];
  _Float16* __restrict__ d = J.dst[j];
  const int n = J.n[j];
  for (int i = blockIdx.x * blockDim.x + threadIdx.x; i < n;
       i += gridDim.x * blockDim.x)
    d[i] = (_Float16)s[i];
}

// ---- GEMM helpers ----
// Vector GEMM: acc[t][c] += W[O][C] * v_c, tiles = wave + 8*t.
template<int TT, int KS>
__device__ __forceinline__ void gemmV(const _Float16* __restrict__ W, int C,
                                      const _Float16* vb, ffrag acc[TT][3]) {
  const int m = threadIdx.x & 15;
  const int q = (threadIdx.x >> 4) & 3;
  const int w = threadIdx.x >> 6;
  #pragma unroll
  for (int ks = 0; ks < KS; ++ks) {
    const int k = ks * 32 + q * 8;
    hfrag b0 = *(const hfrag*)(vb + 0 * PLANE + m * VSTR + k);
    hfrag b1 = *(const hfrag*)(vb + 1 * PLANE + m * VSTR + k);
    hfrag b2 = *(const hfrag*)(vb + 2 * PLANE + m * VSTR + k);
    #pragma unroll
    for (int t = 0; t < TT; ++t) {
      const int row = (w + t * 8) * 16 + m;
      hfrag a = *(const hfrag*)(W + (size_t)row * C + k);
      acc[t][0] = mfma(a, b0, acc[t][0]);
      acc[t][1] = mfma(a, b1, acc[t][1]);
      acc[t][2] = mfma(a, b2, acc[t][2]);
    }
  }
}

// Scalar GEMM: acc[t] += W[O][C] * s
template<int TT, int KS>
__device__ __forceinline__ void gemmS(const _Float16* __restrict__ W, int C,
                                      const _Float16* sb, int sstr, ffrag acc[TT]) {
  const int m = threadIdx.x & 15;
  const int q = (threadIdx.x >> 4) & 3;
  const int w = threadIdx.x >> 6;
  #pragma unroll
  for (int ks = 0; ks < KS; ++ks) {
    const int k = ks * 32 + q * 8;
    hfrag b = *(const hfrag*)(sb + m * sstr + k);
    #pragma unroll
    for (int t = 0; t < TT; ++t) {
      const int row = (w + t * 8) * 16 + m;
      hfrag a = *(const hfrag*)(W + (size_t)row * C + k);
      acc[t] = mfma(a, b, acc[t]);
    }
  }
}

// Store a C/D fragment into an [e][k] LDS buffer (4 consecutive k = rows).
__device__ __forceinline__ void stCD(_Float16* buf, int stride, int tile, ffrag v) {
  const int e = threadIdx.x & 15;
  const int q = (threadIdx.x >> 4) & 3;
  h4 p;
  p[0] = (_Float16)v[0]; p[1] = (_Float16)v[1];
  p[2] = (_Float16)v[2]; p[3] = (_Float16)v[3];
  *(h4*)(buf + e * stride + tile * 16 + q * 4) = p;
}

__device__ __forceinline__ float sigm(float x) { return 1.f / (1.f + expf(-x)); }

__global__ __launch_bounds__(TPB, 4) void pe_kernel(
    const float* __restrict__ h_sca, const float* __restrict__ h_vec,
    const float* __restrict__ pos_compose, const float* __restrict__ pos,
    WB W, const int* __restrict__ idx_focal, float* __restrict__ out, int F) {
  // Single vector buffer: contents progress v_in -> vh -> v_new -> v_final
  // within each layer; every transition is barrier-separated.
  __shared__ _Float16 sv [3 * PLANE];     // [comp][e][k]
  __shared__ _Float16 scat[E * SSTR];     // [vnorm | s | inner] per element
  __shared__ _Float16 souts[E * OSTR];    // raw out_s
  __shared__ float srel[E * 3];

  const int t = threadIdx.x;
  const int wv = t >> 6;          // 0..7
  const int q = (t >> 4) & 3;
  const int el = t >> 5;          // gather: element handled by 32 threads
  const int c5 = t & 31;
  const int eg = blockIdx.x * E + el;

  // ======== gather (f32 -> f16 LDS, float4 loads, h4 stores) ========
  {
    const int idx = (eg < F) ? idx_focal[eg] : 0;
    if (c5 < 16) {
      // h_vec row = 64 cols x 3 comps; thread u=c5 handles cols 4u..4u+3
      const float4* __restrict__ vsrc = (const float4*)(h_vec + (size_t)idx * 192);
      const float4 va = vsrc[3 * c5 + 0];
      const float4 vb = vsrc[3 * c5 + 1];
      const float4 vc = vsrc[3 * c5 + 2];
      const float f[12] = {va.x, va.y, va.z, va.w, vb.x, vb.y, vb.z, vb.w,
                           vc.x, vc.y, vc.z, vc.w};
      #pragma unroll
      for (int comp = 0; comp < 3; ++comp) {
        h4 p;
        p[0] = (_Float16)f[0 + comp]; p[1] = (_Float16)f[3 + comp];
        p[2] = (_Float16)f[6 + comp]; p[3] = (_Float16)f[9 + comp];
        *(h4*)(sv + comp * PLANE + el * VSTR + 4 * c5) = p;
      }
      if (c5 < 3 && eg < F)
        srel[el * 3 + c5] = pos[(size_t)eg * 3 + c5] - pos_compose[(size_t)idx * 3 + c5];
    } else {
      // h_sca row = 256 floats; thread u handles cols 16u..16u+15
      const int u = c5 - 16;
      const float4* __restrict__ ssrc = (const float4*)(h_sca + (size_t)idx * 256);
      #pragma unroll
      for (int i2 = 0; i2 < 4; ++i2) {
        const float4 vv = ssrc[4 * u + i2];
        h4 p;
        p[0] = (_Float16)vv.x; p[1] = (_Float16)vv.y;
        p[2] = (_Float16)vv.z; p[3] = (_Float16)vv.w;
        *(h4*)(scat + el * SSTR + 128 + 16 * u + 4 * i2) = p;
      }
    }
  }
  __syncthreads();

  ffrag zero = {0.f, 0.f, 0.f, 0.f};

  // ================= g1: perceptron (C=64 -> H=128 -> O=128) =================
  {
    ffrag vh[1][3];
    for (int c = 0; c < 3; ++c) vh[0][c] = zero;
    gemmV<1, 2>(W.g1_Wvh, 64, sv, vh);          // reads sv = v_in
    __syncthreads();                            // sv reads done
    {
      for (int c = 0; c < 3; ++c) stCD(sv + c * PLANE, VSTR, wv, vh[0][c]); // vh -> sv
      ffrag n;
      #pragma unroll
      for (int r = 0; r < 4; ++r)
        n[r] = sqrtf(vh[0][0][r]*vh[0][0][r] + vh[0][1][r]*vh[0][1][r] + vh[0][2][r]*vh[0][2][r]);
      stCD(scat, SSTR, wv, n);                  // vnorm -> scat[0:128]
    }
    __syncthreads();                            // vh + vnorm visible

    ffrag so[1]; so[0] = zero;
    ffrag ov[1][3];
    for (int c = 0; c < 3; ++c) ov[0][c] = zero;
    gemmS<1, 12>(W.g1_Ws, 384, scat, SSTR, so); // reads scat (vnorm|s_in)
    gemmV<1, 4>(W.g1_Wvo, 128, sv, ov);         // reads vh
    __syncthreads();                            // scat + sv reads done
    {
      stCD(souts, OSTR, wv, so[0]);             // raw out_s
      ffrag l;
      for (int r = 0; r < 4; ++r) { float x = so[0][r]; l[r] = x >= 0.f ? x : SLOPE_SCA * x; }
      stCD(scat + 128, SSTR, wv, l);            // s for g2 at [128:256]
    }
    __syncthreads();                            // souts visible

    ffrag g[1]; g[0] = zero;
    gemmS<1, 4>(W.g1_Wg, 128, souts, OSTR, g);
    {
      const float4 b = *(const float4*)(W.g1_bg + wv * 16 + q * 4);
      const float bb[4] = {b.x, b.y, b.z, b.w};
      #pragma unroll
      for (int r = 0; r < 4; ++r) {
        float gg = sigm(g[0][r] + bb[r]);
        ov[0][0][r] *= gg; ov[0][1][r] *= gg; ov[0][2][r] *= gg;
      }
      for (int c = 0; c < 3; ++c) stCD(sv + c * PLANE, VSTR, wv, ov[0][c]); // v_new -> sv
    }
    __syncthreads();                            // v_new visible

    ffrag d[1][3];
    for (int c = 0; c < 3; ++c) d[0][c] = zero;
    gemmV<1, 4>(W.g1_Wd, 128, sv, d);           // reads v_new
    __syncthreads();                            // v_new reads done
    {
      #pragma unroll
      for (int r = 0; r < 4; ++r) {
        float x0 = ov[0][0][r], x1 = ov[0][1][r], x2 = ov[0][2][r];
        float d0 = d[0][0][r],  d1 = d[0][1][r],  d2 = d[0][2][r];
        float dot = x0*d0 + x1*d1 + x2*d2;
        float kk = dot / (d0*d0 + d1*d1 + d2*d2 + EPS_VN);
        if (dot < 0.f) {
          ov[0][0][r] = SLOPE_VN*x0 + (1.f-SLOPE_VN)*(x0 - kk*d0);
          ov[0][1][r] = SLOPE_VN*x1 + (1.f-SLOPE_VN)*(x1 - kk*d1);
          ov[0][2][r] = SLOPE_VN*x2 + (1.f-SLOPE_VN)*(x2 - kk*d2);
        }
      }
      for (int c = 0; c < 3; ++c) stCD(sv + c * PLANE, VSTR, wv, ov[0][c]); // v_final
    }
    __syncthreads();
  }

  // ================= g2: linear (128 -> 128) =================
  {
    ffrag vh[1][3];
    for (int c = 0; c < 3; ++c) vh[0][c] = zero;
    gemmV<1, 4>(W.g2_Wvh, 128, sv, vh);
    __syncthreads();
    {
      for (int c = 0; c < 3; ++c) stCD(sv + c * PLANE, VSTR, wv, vh[0][c]);
      ffrag n;
      for (int r = 0; r < 4; ++r)
        n[r] = sqrtf(vh[0][0][r]*vh[0][0][r] + vh[0][1][r]*vh[0][1][r] + vh[0][2][r]*vh[0][2][r]);
      stCD(scat, SSTR, wv, n);
    }
    __syncthreads();

    ffrag so[1]; so[0] = zero;
    ffrag ov[1][3];
    for (int c = 0; c < 3; ++c) ov[0][c] = zero;
    gemmS<1, 8>(W.g2_Ws, 256, scat, SSTR, so);
    gemmV<1, 4>(W.g2_Wvo, 128, sv, ov);
    __syncthreads();
    {
      stCD(souts, OSTR, wv, so[0]);
      stCD(scat + 256, SSTR, wv, so[0]);        // s for a1 at [256:384], no act
    }
    __syncthreads();

    ffrag g[1]; g[0] = zero;
    gemmS<1, 4>(W.g2_Wg, 128, souts, OSTR, g);
    {
      const float4 b = *(const float4*)(W.g2_bg + wv * 16 + q * 4);
      const float bb[4] = {b.x, b.y, b.z, b.w};
      for (int r = 0; r < 4; ++r) {
        float gg = sigm(g[0][r] + bb[r]);
        ov[0][0][r] *= gg; ov[0][1][r] *= gg; ov[0][2][r] *= gg;
      }
      for (int c = 0; c < 3; ++c) stCD(sv + c * PLANE, VSTR, wv, ov[0][c]);
    }
    __syncthreads();
  }

  // ================= a1: perceptron (128 -> H=256 -> O=256) =================
  {
    ffrag vh[2][3];
    #pragma unroll
    for (int i = 0; i < 2; ++i) for (int c = 0; c < 3; ++c) vh[i][c] = zero;
    gemmV<2, 4>(W.a1_Wvh, 128, sv, vh);
    __syncthreads();
    #pragma unroll
    for (int i = 0; i < 2; ++i) {
      const int tile = wv + i * 8;
      for (int c = 0; c < 3; ++c) stCD(sv + c * PLANE, VSTR, tile, vh[i][c]);
      ffrag n;
      for (int r = 0; r < 4; ++r)
        n[r] = sqrtf(vh[i][0][r]*vh[i][0][r] + vh[i][1][r]*vh[i][1][r] + vh[i][2][r]*vh[i][2][r]);
      stCD(scat, SSTR, tile, n);                // vnorm -> scat[0:256]
    }
    __syncthreads();

    ffrag so[1]; so[0] = zero;
    ffrag ov[2][3];
    #pragma unroll
    for (int i = 0; i < 2; ++i) for (int c = 0; c < 3; ++c) ov[i][c] = zero;
    gemmS<1, 12>(W.a1_Ws, 384, scat, SSTR, so);
    gemmV<2, 8>(W.a1_Wvo, 256, sv, ov);         // reads vh (256-wide)
    __syncthreads();
    {
      stCD(souts, OSTR, wv, so[0]);
      ffrag l;
      for (int r = 0; r < 4; ++r) { float x = so[0][r]; l[r] = x >= 0.f ? x : SLOPE_SCA * x; }
      stCD(scat + 128, SSTR, wv, l);            // s1 for a2 at [128:256]
    }
    __syncthreads();

    ffrag g[2];
    #pragma unroll
    for (int i = 0; i < 2; ++i) g[i] = zero;
    gemmS<2, 4>(W.a1_Wg, 128, souts, OSTR, g);
    #pragma unroll
    for (int i = 0; i < 2; ++i) {
      const int tile = wv + i * 8;
      const float4 b = *(const float4*)(W.a1_bg + tile * 16 + q * 4);
      const float bb[4] = {b.x, b.y, b.z, b.w};
      for (int r = 0; r < 4; ++r) {
        float gg = sigm(g[i][r] + bb[r]);
        ov[i][0][r] *= gg; ov[i][1][r] *= gg; ov[i][2][r] *= gg;
      }
      for (int c = 0; c < 3; ++c) stCD(sv + c * PLANE, VSTR, tile, ov[i][c]); // v_new
    }
    __syncthreads();

    ffrag d[2][3];
    #pragma unroll
    for (int i = 0; i < 2; ++i) for (int c = 0; c < 3; ++c) d[i][c] = zero;
    gemmV<2, 8>(W.a1_Wd, 256, sv, d);
    __syncthreads();
    #pragma unroll
    for (int i = 0; i < 2; ++i) {
      for (int r = 0; r < 4; ++r) {
        float x0 = ov[i][0][r], x1 = ov[i][1][r], x2 = ov[i][2][r];
        float d0 = d[i][0][r],  d1 = d[i][1][r],  d2 = d[i][2][r];
        float dot = x0*d0 + x1*d1 + x2*d2;
        float kk = dot / (d0*d0 + d1*d1 + d2*d2 + EPS_VN);
        if (dot < 0.f) {
          ov[i][0][r] = SLOPE_VN*x0 + (1.f-SLOPE_VN)*(x0 - kk*d0);
          ov[i][1][r] = SLOPE_VN*x1 + (1.f-SLOPE_VN)*(x1 - kk*d1);
          ov[i][2][r] = SLOPE_VN*x2 + (1.f-SLOPE_VN)*(x2 - kk*d2);
        }
      }
      for (int c = 0; c < 3; ++c) stCD(sv + c * PLANE, VSTR, wv + i * 8, ov[i][c]); // v1
    }
    __syncthreads();
  }

  // ---- mid: inner[e][h] = <v1[128+h], relpos[e]> -> scat[256:384] ----
  {
    const float r0 = srel[el * 3 + 0], r1 = srel[el * 3 + 1], r2 = srel[el * 3 + 2];
    for (int h = c5; h < 128; h += 32) {
      float x0 = (float)sv[0 * PLANE + el * VSTR + 128 + h];
      float x1 = (float)sv[1 * PLANE + el * VSTR + 128 + h];
      float x2 = (float)sv[2 * PLANE + el * VSTR + 128 + h];
      scat[el * SSTR + 256 + h] = (_Float16)(x0 * r0 + x1 * r1 + x2 * r2);
    }
  }
  // no barrier: a2's Wvh gemm below only READS sv[0:128]; the barrier after it
  // covers mid's reads/writes before any LDS overwrite.

  // ================= a2: perceptron (v = v1[:,:128], s2 = [s1, inner]) =========
  {
    ffrag vh[1][3];
    for (int c = 0; c < 3; ++c) vh[0][c] = zero;
    gemmV<1, 4>(W.a2_Wvh, 128, sv, vh);
    __syncthreads();                            // sv reads + mid writes done
    {
      for (int c = 0; c < 3; ++c) stCD(sv + c * PLANE, VSTR, wv, vh[0][c]);
      ffrag n;
      for (int r = 0; r < 4; ++r)
        n[r] = sqrtf(vh[0][0][r]*vh[0][0][r] + vh[0][1][r]*vh[0][1][r] + vh[0][2][r]*vh[0][2][r]);
      stCD(scat, SSTR, wv, n);
    }
    __syncthreads();

    ffrag so[1]; so[0] = zero;
    ffrag ov[1][3];
    for (int c = 0; c < 3; ++c) ov[0][c] = zero;
    gemmS<1, 12>(W.a2_Ws, 384, scat, SSTR, so);
    gemmV<1, 4>(W.a2_Wvo, 128, sv, ov);
    __syncthreads();
    {
      stCD(souts, OSTR, wv, so[0]);
      ffrag l;
      for (int r = 0; r < 4; ++r) { float x = so[0][r]; l[r] = x >= 0.f ? x : SLOPE_SCA * x; }
      stCD(scat + 128, SSTR, wv, l);            // s_a2 for f at [128:256]
    }
    __syncthreads();

    ffrag g[1]; g[0] = zero;
    gemmS<1, 4>(W.a2_Wg, 128, souts, OSTR, g);
    {
      const float4 b = *(const float4*)(W.a2_bg + wv * 16 + q * 4);
      const float bb[4] = {b.x, b.y, b.z, b.w};
      for (int r = 0; r < 4; ++r) {
        float gg = sigm(g[0][r] + bb[r]);
        ov[0][0][r] *= gg; ov[0][1][r] *= gg; ov[0][2][r] *= gg;
      }
      for (int c = 0; c < 3; ++c) stCD(sv + c * PLANE, VSTR, wv, ov[0][c]);
    }
    __syncthreads();

    ffrag d[1][3];
    for (int c = 0; c < 3; ++c) d[0][c] = zero;
    gemmV<1, 4>(W.a2_Wd, 128, sv, d);
    __syncthreads();
    {
      for (int r = 0; r < 4; ++r) {
        float x0 = ov[0][0][r], x1 = ov[0][1][r], x2 = ov[0][2][r];
        float d0 = d[0][0][r],  d1 = d[0][1][r],  d2 = d[0][2][r];
        float dot = x0*d0 + x1*d1 + x2*d2;
        float kk = dot / (d0*d0 + d1*d1 + d2*d2 + EPS_VN);
        if (dot < 0.f) {
          ov[0][0][r] = SLOPE_VN*x0 + (1.f-SLOPE_VN)*(x0 - kk*d0);
          ov[0][1][r] = SLOPE_VN*x1 + (1.f-SLOPE_VN)*(x1 - kk*d1);
          ov[0][2][r] = SLOPE_VN*x2 + (1.f-SLOPE_VN)*(x2 - kk*d2);
        }
      }
      for (int c = 0; c < 3; ++c) stCD(sv + c * PLANE, VSTR, wv, ov[0][c]);
    }
    __syncthreads();
  }

  // ================= f: vnorm + final dot =================
  {
    ffrag vh[1][3];
    for (int c = 0; c < 3; ++c) vh[0][c] = zero;
    gemmV<1, 4>(W.f_Wvh, 128, sv, vh);
    {
      ffrag n;
      for (int r = 0; r < 4; ++r)
        n[r] = sqrtf(vh[0][0][r]*vh[0][0][r] + vh[0][1][r]*vh[0][1][r] + vh[0][2][r]*vh[0][2][r]);
      stCD(scat, SSTR, wv, n);
    }
    __syncthreads();

    float part = 0.f;
    for (int c = c5; c < 256; c += 32)
      part += (float)scat[el * SSTR + c] * W.f_Ws[c];
    part += __shfl_xor(part, 16, 32);
    part += __shfl_xor(part, 8, 32);
    part += __shfl_xor(part, 4, 32);
    part += __shfl_xor(part, 2, 32);
    part += __shfl_xor(part, 1, 32);
    if (c5 == 0 && eg < F) out[eg] = part;
  }
}

extern "C" void kernel_launch(void* const* d_in, const int* in_sizes, int n_in,
                              void* d_out, int out_size, void* d_ws, size_t ws_size,
                              hipStream_t stream) {
  const float* h_sca       = (const float*)d_in[0];
  const float* h_vec       = (const float*)d_in[1];
  const float* pos_compose = (const float*)d_in[2];
  const float* pos         = (const float*)d_in[3];
  const int* idx_focal     = (const int*)d_in[29];
  const int F = in_sizes[29];

  // weight conversion jobs: d_in index -> packed f16 in d_ws
  const int widx[20] = {4,5,6,7,9, 10,11,12,13, 15,16,17,18,20, 21,22,23,24,26, 27};
  CvtJobs J;
  _Float16* wsp = (_Float16*)d_ws;
  size_t off = 0;
  const _Float16* wptr[20];
  for (int j = 0; j < 20; ++j) {
    J.src[j] = (const float*)d_in[widx[j]];
    J.dst[j] = wsp + off;
    J.n[j]   = in_sizes[widx[j]];
    wptr[j]  = wsp + off;
    off += in_sizes[widx[j]];
  }
  cvt_kernel<<<dim3(32, 20), dim3(256), 0, stream>>>(J);

  WB W;
  W.g1_Wvh = wptr[0];  W.g1_Ws = wptr[1];  W.g1_Wvo = wptr[2];  W.g1_Wg = wptr[3];  W.g1_Wd = wptr[4];
  W.g2_Wvh = wptr[5];  W.g2_Ws = wptr[6];  W.g2_Wvo = wptr[7];  W.g2_Wg = wptr[8];
  W.a1_Wvh = wptr[9];  W.a1_Ws = wptr[10]; W.a1_Wvo = wptr[11]; W.a1_Wg = wptr[12]; W.a1_Wd = wptr[13];
  W.a2_Wvh = wptr[14]; W.a2_Ws = wptr[15]; W.a2_Wvo = wptr[16]; W.a2_Wg = wptr[17]; W.a2_Wd = wptr[18];
  W.f_Wvh  = wptr[19];
  W.g1_bg = (const float*)d_in[8];
  W.g2_bg = (const float*)d_in[14];
  W.a1_bg = (const float*)d_in[19];
  W.a2_bg = (const float*)d_in[25];
  W.f_Ws  = (const float*)d_in[28];

  const int blocks = (F + E - 1) / E;
  pe_kernel<<<dim3(blocks), dim3(TPB), 0, stream>>>(
      h_sca, h_vec, pos_compose, pos, W, idx_focal, (float*)d_out, F);
}

// Round 4
// 1099.569 us; speedup vs baseline: 1.0361x; 1.0169x over previous
//
#include <hip/hip_runtime.h>
#include <math.h>

#define TPB 512        // 8 waves: wave w owns row-tile (w + t*8)
#define E 16           // elements per block
#define VSTR 264       // [e][k] stride for vector-activation LDS buffers (f16)
#define PLANE (E * VSTR)
#define SSTR 392       // scat stride
#define OSTR 136       // souts stride
#define SLOPE_VN 0.2f
#define SLOPE_SCA 0.01f
#define EPS_VN 1e-6f

using hfrag = __attribute__((ext_vector_type(8))) _Float16;
using h4    = __attribute__((ext_vector_type(4))) _Float16;
using ffrag = __attribute__((ext_vector_type(4))) float;

__device__ __forceinline__ ffrag mfma(hfrag a, hfrag b, ffrag c) {
  return __builtin_amdgcn_mfma_f32_16x16x32_f16(a, b, c, 0, 0, 0);
}

// ---- f16 weight pointers (into d_ws) ----
struct WB {
  const _Float16 *g1_Wvh,*g1_Ws,*g1_Wvo,*g1_Wg,*g1_Wd;
  const _Float16 *g2_Wvh,*g2_Ws,*g2_Wvo,*g2_Wg;
  const _Float16 *a1_Wvh,*a1_Ws,*a1_Wvo,*a1_Wg,*a1_Wd;
  const _Float16 *a2_Wvh,*a2_Ws,*a2_Wvo,*a2_Wg,*a2_Wd;
  const _Float16 *f_Wvh;
  const float *g1_bg,*g2_bg,*a1_bg,*a2_bg,*f_Ws;
};

// ---- weight f32->f16 conversion pre-pass ----
struct CvtJobs { const float* src[20]; _Float16* dst[20]; int n[20]; };

__global__ void cvt_kernel(CvtJobs J) {
  const int j = blockIdx.y;
  const float* __restrict__ s = J.src[j];
  _Float16* __restrict__ d = J.dst[j];
  const int n = J.n[j];
  for (int i = blockIdx.x * blockDim.x + threadIdx.x; i < n;
       i += gridDim.x * blockDim.x)
    d[i] = (_Float16)s[i];
}

// ---- GEMM helpers ----
// Vector GEMM: acc[t][c] += W[O][C] * v_c, tiles = wave + 8*t.
template<int TT, int KS>
__device__ __forceinline__ void gemmV(const _Float16* __restrict__ W, int C,
                                      const _Float16* vb, ffrag acc[TT][3]) {
  const int m = threadIdx.x & 15;
  const int q = (threadIdx.x >> 4) & 3;
  const int w = threadIdx.x >> 6;
  #pragma unroll
  for (int ks = 0; ks < KS; ++ks) {
    const int k = ks * 32 + q * 8;
    hfrag b0 = *(const hfrag*)(vb + 0 * PLANE + m * VSTR + k);
    hfrag b1 = *(const hfrag*)(vb + 1 * PLANE + m * VSTR + k);
    hfrag b2 = *(const hfrag*)(vb + 2 * PLANE + m * VSTR + k);
    #pragma unroll
    for (int t = 0; t < TT; ++t) {
      const int row = (w + t * 8) * 16 + m;
      hfrag a = *(const hfrag*)(W + (size_t)row * C + k);
      acc[t][0] = mfma(a, b0, acc[t][0]);
      acc[t][1] = mfma(a, b1, acc[t][1]);
      acc[t][2] = mfma(a, b2, acc[t][2]);
    }
  }
}

// Scalar GEMM: acc[t] += W[O][C] * s
template<int TT, int KS>
__device__ __forceinline__ void gemmS(const _Float16* __restrict__ W, int C,
                                      const _Float16* sb, int sstr, ffrag acc[TT]) {
  const int m = threadIdx.x & 15;
  const int q = (threadIdx.x >> 4) & 3;
  const int w = threadIdx.x >> 6;
  #pragma unroll
  for (int ks = 0; ks < KS; ++ks) {
    const int k = ks * 32 + q * 8;
    hfrag b = *(const hfrag*)(sb + m * sstr + k);
    #pragma unroll
    for (int t = 0; t < TT; ++t) {
      const int row = (w + t * 8) * 16 + m;
      hfrag a = *(const hfrag*)(W + (size_t)row * C + k);
      acc[t] = mfma(a, b, acc[t]);
    }
  }
}

// Store a C/D fragment into an [e][k] LDS buffer (4 consecutive k = rows).
__device__ __forceinline__ void stCD(_Float16* buf, int stride, int tile, ffrag v) {
  const int e = threadIdx.x & 15;
  const int q = (threadIdx.x >> 4) & 3;
  h4 p;
  p[0] = (_Float16)v[0]; p[1] = (_Float16)v[1];
  p[2] = (_Float16)v[2]; p[3] = (_Float16)v[3];
  *(h4*)(buf + e * stride + tile * 16 + q * 4) = p;
}

// Re-load a C/D fragment (this wave's own tile) from LDS.
__device__ __forceinline__ ffrag ldCD(const _Float16* buf, int stride, int tile) {
  const int e = threadIdx.x & 15;
  const int q = (threadIdx.x >> 4) & 3;
  h4 p = *(const h4*)(buf + e * stride + tile * 16 + q * 4);
  ffrag v;
  v[0] = (float)p[0]; v[1] = (float)p[1]; v[2] = (float)p[2]; v[3] = (float)p[3];
  return v;
}

__device__ __forceinline__ float sigm(float x) { return 1.f / (1.f + expf(-x)); }

// vn_leaky on re-read x (f16, self-consistent with Wd input) + d, store result.
__device__ __forceinline__ void vnLeakyStore(_Float16* sv, int tile,
                                             ffrag d0, ffrag d1, ffrag d2) {
  ffrag x0 = ldCD(sv + 0 * PLANE, VSTR, tile);
  ffrag x1 = ldCD(sv + 1 * PLANE, VSTR, tile);
  ffrag x2 = ldCD(sv + 2 * PLANE, VSTR, tile);
  #pragma unroll
  for (int r = 0; r < 4; ++r) {
    float dot = x0[r]*d0[r] + x1[r]*d1[r] + x2[r]*d2[r];
    float kk = dot / (d0[r]*d0[r] + d1[r]*d1[r] + d2[r]*d2[r] + EPS_VN);
    if (dot < 0.f) {
      x0[r] = SLOPE_VN*x0[r] + (1.f-SLOPE_VN)*(x0[r] - kk*d0[r]);
      x1[r] = SLOPE_VN*x1[r] + (1.f-SLOPE_VN)*(x1[r] - kk*d1[r]);
      x2[r] = SLOPE_VN*x2[r] + (1.f-SLOPE_VN)*(x2[r] - kk*d2[r]);
    }
  }
  stCD(sv + 0 * PLANE, VSTR, tile, x0);
  stCD(sv + 1 * PLANE, VSTR, tile, x1);
  stCD(sv + 2 * PLANE, VSTR, tile, x2);
}

__global__ __launch_bounds__(TPB, 6) void pe_kernel(
    const float* __restrict__ h_sca, const float* __restrict__ h_vec,
    const float* __restrict__ pos_compose, const float* __restrict__ pos,
    WB W, const int* __restrict__ idx_focal, float* __restrict__ out, int F) {
  // sv: [comp][e][k<264]. Region use per layer:
  //   g1: v_in [0:64], vh [64:192], v_new/final [0:128]
  //   g2: v_in [0:128], vh [128:256], v_final [0:128]
  //   a1: v_in [0:128], vh/v_new/v1 [0:256]
  //   a2: v_in [0:128], vh [128:256], v_new/final [0:128]
  // scat: [e][k<392]:
  //   g1 Ws in: vnorm[0:128]|s_in[128:384];  g1 act_s -> [128:256]
  //   g2 Ws in: vnorm[0:128]|act_s[128:256]; g2 raw_so -> [256:384]
  //   a1 Ws in: vnorm[0:256]|raw_so_g2[256:384]; a1 act_s1 -> [128:256]
  //   a2 Ws in: vnorm[0:128]|s1[128:256]|inner[256:384]; a2 act_s -> [128:256]
  //   f  in:    vnorm[0:128]|act_s[128:256]
  __shared__ _Float16 sv [3 * PLANE];
  __shared__ _Float16 scat[E * SSTR];
  __shared__ _Float16 souts[E * OSTR];    // raw out_s (g1/a1/a2)
  __shared__ float srel[E * 3];

  const int t = threadIdx.x;
  const int wv = t >> 6;          // 0..7
  const int q = (t >> 4) & 3;
  const int el = t >> 5;          // gather: element handled by 32 threads
  const int c5 = t & 31;
  const int eg = blockIdx.x * E + el;

  // ======== gather (f32 -> f16 LDS, float4 loads, h4 stores) ========
  {
    const int idx = (eg < F) ? idx_focal[eg] : 0;
    if (c5 < 16) {
      const float4* __restrict__ vsrc = (const float4*)(h_vec + (size_t)idx * 192);
      const float4 va = vsrc[3 * c5 + 0];
      const float4 vb = vsrc[3 * c5 + 1];
      const float4 vc = vsrc[3 * c5 + 2];
      const float f[12] = {va.x, va.y, va.z, va.w, vb.x, vb.y, vb.z, vb.w,
                           vc.x, vc.y, vc.z, vc.w};
      #pragma unroll
      for (int comp = 0; comp < 3; ++comp) {
        h4 p;
        p[0] = (_Float16)f[0 + comp]; p[1] = (_Float16)f[3 + comp];
        p[2] = (_Float16)f[6 + comp]; p[3] = (_Float16)f[9 + comp];
        *(h4*)(sv + comp * PLANE + el * VSTR + 4 * c5) = p;
      }
      if (c5 < 3 && eg < F)
        srel[el * 3 + c5] = pos[(size_t)eg * 3 + c5] - pos_compose[(size_t)idx * 3 + c5];
    } else {
      const int u = c5 - 16;
      const float4* __restrict__ ssrc = (const float4*)(h_sca + (size_t)idx * 256);
      #pragma unroll
      for (int i2 = 0; i2 < 4; ++i2) {
        const float4 vv = ssrc[4 * u + i2];
        h4 p;
        p[0] = (_Float16)vv.x; p[1] = (_Float16)vv.y;
        p[2] = (_Float16)vv.z; p[3] = (_Float16)vv.w;
        *(h4*)(scat + el * SSTR + 128 + 16 * u + 4 * i2) = p;
      }
    }
  }
  __syncthreads();

  ffrag zero = {0.f, 0.f, 0.f, 0.f};

  // ================= g1: perceptron (C=64 -> H=128 -> O=128) =================
  {
    // A: vh = Wvh @ v_in; vh -> sv[64:192] (not read here), vnorm -> scat[0:128]
    ffrag vh[1][3];
    for (int c = 0; c < 3; ++c) vh[0][c] = zero;
    gemmV<1, 2>(W.g1_Wvh, 64, sv, vh);
    for (int c = 0; c < 3; ++c) stCD(sv + c * PLANE + 64, VSTR, wv, vh[0][c]);
    {
      ffrag n;
      #pragma unroll
      for (int r = 0; r < 4; ++r)
        n[r] = sqrtf(vh[0][0][r]*vh[0][0][r] + vh[0][1][r]*vh[0][1][r] + vh[0][2][r]*vh[0][2][r]);
      stCD(scat, SSTR, wv, n);
    }
    __syncthreads();

    // B: so = Ws @ scat[0:384]; ov = Wvo @ vh; raw_so -> souts
    ffrag so[1]; so[0] = zero;
    ffrag ov[1][3];
    for (int c = 0; c < 3; ++c) ov[0][c] = zero;
    gemmS<1, 12>(W.g1_Ws, 384, scat, SSTR, so);
    gemmV<1, 4>(W.g1_Wvo, 128, sv + 64, ov);
    stCD(souts, OSTR, wv, so[0]);
    __syncthreads();

    // C: g = Wg @ souts; gate; v_new -> sv[0:128]; act_s -> scat[128:256]
    ffrag g[1]; g[0] = zero;
    gemmS<1, 4>(W.g1_Wg, 128, souts, OSTR, g);
    {
      const float4 b = *(const float4*)(W.g1_bg + wv * 16 + q * 4);
      const float bb[4] = {b.x, b.y, b.z, b.w};
      #pragma unroll
      for (int r = 0; r < 4; ++r) {
        float gg = sigm(g[0][r] + bb[r]);
        ov[0][0][r] *= gg; ov[0][1][r] *= gg; ov[0][2][r] *= gg;
      }
      for (int c = 0; c < 3; ++c) stCD(sv + c * PLANE, VSTR, wv, ov[0][c]);
      ffrag l;
      for (int r = 0; r < 4; ++r) { float x = so[0][r]; l[r] = x >= 0.f ? x : SLOPE_SCA * x; }
      stCD(scat + 128, SSTR, wv, l);
    }
    __syncthreads();

    // D: d = Wd @ v_new
    ffrag d[1][3];
    for (int c = 0; c < 3; ++c) d[0][c] = zero;
    gemmV<1, 4>(W.g1_Wd, 128, sv, d);
    __syncthreads();

    // E: vn_leaky (x re-read from sv), v_final -> sv[0:128]
    vnLeakyStore(sv, wv, d[0][0], d[0][1], d[0][2]);
    __syncthreads();
  }

  // ================= g2: linear (128 -> 128) =================
  {
    // A: vh -> sv[128:256]; vnorm -> scat[0:128]
    ffrag vh[1][3];
    for (int c = 0; c < 3; ++c) vh[0][c] = zero;
    gemmV<1, 4>(W.g2_Wvh, 128, sv, vh);
    for (int c = 0; c < 3; ++c) stCD(sv + c * PLANE + 128, VSTR, wv, vh[0][c]);
    {
      ffrag n;
      for (int r = 0; r < 4; ++r)
        n[r] = sqrtf(vh[0][0][r]*vh[0][0][r] + vh[0][1][r]*vh[0][1][r] + vh[0][2][r]*vh[0][2][r]);
      stCD(scat, SSTR, wv, n);
    }
    __syncthreads();

    // B: so = Ws @ scat[0:256]; ov = Wvo @ vh; raw_so -> scat[256:384] (a1 input + Wg input)
    ffrag so[1]; so[0] = zero;
    ffrag ov[1][3];
    for (int c = 0; c < 3; ++c) ov[0][c] = zero;
    gemmS<1, 8>(W.g2_Ws, 256, scat, SSTR, so);
    gemmV<1, 4>(W.g2_Wvo, 128, sv + 128, ov);
    stCD(scat + 256, SSTR, wv, so[0]);
    __syncthreads();

    // C: g = Wg @ scat[256:384]; gate; v_final -> sv[0:128]
    ffrag g[1]; g[0] = zero;
    gemmS<1, 4>(W.g2_Wg, 128, scat + 256, SSTR, g);
    {
      const float4 b = *(const float4*)(W.g2_bg + wv * 16 + q * 4);
      const float bb[4] = {b.x, b.y, b.z, b.w};
      for (int r = 0; r < 4; ++r) {
        float gg = sigm(g[0][r] + bb[r]);
        ov[0][0][r] *= gg; ov[0][1][r] *= gg; ov[0][2][r] *= gg;
      }
      for (int c = 0; c < 3; ++c) stCD(sv + c * PLANE, VSTR, wv, ov[0][c]);
    }
    __syncthreads();
  }

  // ================= a1: perceptron (128 -> H=256 -> O=256) =================
  {
    // A: vh[2] = Wvh @ v (needs [0:256], overlaps v_in -> barrier then store)
    ffrag vh[2][3];
    #pragma unroll
    for (int i = 0; i < 2; ++i) for (int c = 0; c < 3; ++c) vh[i][c] = zero;
    gemmV<2, 4>(W.a1_Wvh, 128, sv, vh);
    __syncthreads();
    #pragma unroll
    for (int i = 0; i < 2; ++i) {
      const int tile = wv + i * 8;
      for (int c = 0; c < 3; ++c) stCD(sv + c * PLANE, VSTR, tile, vh[i][c]);
      ffrag n;
      for (int r = 0; r < 4; ++r)
        n[r] = sqrtf(vh[i][0][r]*vh[i][0][r] + vh[i][1][r]*vh[i][1][r] + vh[i][2][r]*vh[i][2][r]);
      stCD(scat, SSTR, tile, n);
    }
    __syncthreads();

    // B: so = Ws @ scat[0:384]; ov[2] = Wvo(256) @ vh; raw_so -> souts
    ffrag so[1]; so[0] = zero;
    ffrag ov[2][3];
    #pragma unroll
    for (int i = 0; i < 2; ++i) for (int c = 0; c < 3; ++c) ov[i][c] = zero;
    gemmS<1, 12>(W.a1_Ws, 384, scat, SSTR, so);
    gemmV<2, 8>(W.a1_Wvo, 256, sv, ov);
    stCD(souts, OSTR, wv, so[0]);
    __syncthreads();

    // C: g[2] = Wg @ souts; gate both tiles; v_new -> sv[0:256]; act_s1 -> scat[128:256]
    ffrag g[2];
    #pragma unroll
    for (int i = 0; i < 2; ++i) g[i] = zero;
    gemmS<2, 4>(W.a1_Wg, 128, souts, OSTR, g);
    #pragma unroll
    for (int i = 0; i < 2; ++i) {
      const int tile = wv + i * 8;
      const float4 b = *(const float4*)(W.a1_bg + tile * 16 + q * 4);
      const float bb[4] = {b.x, b.y, b.z, b.w};
      for (int r = 0; r < 4; ++r) {
        float gg = sigm(g[i][r] + bb[r]);
        ov[i][0][r] *= gg; ov[i][1][r] *= gg; ov[i][2][r] *= gg;
      }
      for (int c = 0; c < 3; ++c) stCD(sv + c * PLANE, VSTR, tile, ov[i][c]);
    }
    {
      ffrag l;
      for (int r = 0; r < 4; ++r) { float x = so[0][r]; l[r] = x >= 0.f ? x : SLOPE_SCA * x; }
      stCD(scat + 128, SSTR, wv, l);
    }
    __syncthreads();

    // D: d[2] = Wd(256) @ v_new
    ffrag d[2][3];
    #pragma unroll
    for (int i = 0; i < 2; ++i) for (int c = 0; c < 3; ++c) d[i][c] = zero;
    gemmV<2, 8>(W.a1_Wd, 256, sv, d);
    __syncthreads();

    // E: vn_leaky per tile (x re-read), v1 -> sv[0:256]
    vnLeakyStore(sv, wv,     d[0][0], d[0][1], d[0][2]);
    vnLeakyStore(sv, wv + 8, d[1][0], d[1][1], d[1][2]);
    __syncthreads();
  }

  // ---- mid: inner[e][h] = <v1[128+h], relpos[e]> -> scat[256:384]
  //      (concurrent with a2's Wvh gemm: disjoint reads/writes) ----
  {
    const float r0 = srel[el * 3 + 0], r1 = srel[el * 3 + 1], r2 = srel[el * 3 + 2];
    for (int h = c5; h < 128; h += 32) {
      float x0 = (float)sv[0 * PLANE + el * VSTR + 128 + h];
      float x1 = (float)sv[1 * PLANE + el * VSTR + 128 + h];
      float x2 = (float)sv[2 * PLANE + el * VSTR + 128 + h];
      scat[el * SSTR + 256 + h] = (_Float16)(x0 * r0 + x1 * r1 + x2 * r2);
    }
  }

  // ================= a2: perceptron (v = v1[:,:128], s2 = [s1, inner]) =========
  {
    // A: vh = Wvh @ sv[0:128] (concurrent with mid above)
    ffrag vh[1][3];
    for (int c = 0; c < 3; ++c) vh[0][c] = zero;
    gemmV<1, 4>(W.a2_Wvh, 128, sv, vh);
    __syncthreads();                  // mid reads of sv[128:256] done
    // A-store: vh -> sv[128:256]; vnorm -> scat[0:128]
    for (int c = 0; c < 3; ++c) stCD(sv + c * PLANE + 128, VSTR, wv, vh[0][c]);
    {
      ffrag n;
      for (int r = 0; r < 4; ++r)
        n[r] = sqrtf(vh[0][0][r]*vh[0][0][r] + vh[0][1][r]*vh[0][1][r] + vh[0][2][r]*vh[0][2][r]);
      stCD(scat, SSTR, wv, n);
    }
    __syncthreads();

    // B: so = Ws @ scat[0:384]; ov = Wvo @ vh; raw_so -> souts
    ffrag so[1]; so[0] = zero;
    ffrag ov[1][3];
    for (int c = 0; c < 3; ++c) ov[0][c] = zero;
    gemmS<1, 12>(W.a2_Ws, 384, scat, SSTR, so);
    gemmV<1, 4>(W.a2_Wvo, 128, sv + 128, ov);
    stCD(souts, OSTR, wv, so[0]);
    __syncthreads();

    // C: g = Wg @ souts; gate; v_new -> sv[0:128]; act_s -> scat[128:256]
    ffrag g[1]; g[0] = zero;
    gemmS<1, 4>(W.a2_Wg, 128, souts, OSTR, g);
    {
      const float4 b = *(const float4*)(W.a2_bg + wv * 16 + q * 4);
      const float bb[4] = {b.x, b.y, b.z, b.w};
      for (int r = 0; r < 4; ++r) {
        float gg = sigm(g[0][r] + bb[r]);
        ov[0][0][r] *= gg; ov[0][1][r] *= gg; ov[0][2][r] *= gg;
      }
      for (int c = 0; c < 3; ++c) stCD(sv + c * PLANE, VSTR, wv, ov[0][c]);
      ffrag l;
      for (int r = 0; r < 4; ++r) { float x = so[0][r]; l[r] = x >= 0.f ? x : SLOPE_SCA * x; }
      stCD(scat + 128, SSTR, wv, l);
    }
    __syncthreads();

    // D: d = Wd @ v_new
    ffrag d[1][3];
    for (int c = 0; c < 3; ++c) d[0][c] = zero;
    gemmV<1, 4>(W.a2_Wd, 128, sv, d);
    __syncthreads();

    // E: vn_leaky, v_final -> sv[0:128]
    vnLeakyStore(sv, wv, d[0][0], d[0][1], d[0][2]);
    __syncthreads();
  }

  // ================= f: vnorm + final dot =================
  {
    ffrag vh[1][3];
    for (int c = 0; c < 3; ++c) vh[0][c] = zero;
    gemmV<1, 4>(W.f_Wvh, 128, sv, vh);
    {
      ffrag n;
      for (int r = 0; r < 4; ++r)
        n[r] = sqrtf(vh[0][0][r]*vh[0][0][r] + vh[0][1][r]*vh[0][1][r] + vh[0][2][r]*vh[0][2][r]);
      stCD(scat, SSTR, wv, n);
    }
    __syncthreads();

    float part = 0.f;
    for (int c = c5; c < 256; c += 32)
      part += (float)scat[el * SSTR + c] * W.f_Ws[c];
    part += __shfl_xor(part, 16, 32);
    part += __shfl_xor(part, 8, 32);
    part += __shfl_xor(part, 4, 32);
    part += __shfl_xor(part, 2, 32);
    part += __shfl_xor(part, 1, 32);
    if (c5 == 0 && eg < F) out[eg] = part;
  }
}

extern "C" void kernel_launch(void* const* d_in, const int* in_sizes, int n_in,
                              void* d_out, int out_size, void* d_ws, size_t ws_size,
                              hipStream_t stream) {
  const float* h_sca       = (const float*)d_in[0];
  const float* h_vec       = (const float*)d_in[1];
  const float* pos_compose = (const float*)d_in[2];
  const float* pos         = (const float*)d_in[3];
  const int* idx_focal     = (const int*)d_in[29];
  const int F = in_sizes[29];

  // weight conversion jobs: d_in index -> packed f16 in d_ws
  const int widx[20] = {4,5,6,7,9, 10,11,12,13, 15,16,17,18,20, 21,22,23,24,26, 27};
  CvtJobs J;
  _Float16* wsp = (_Float16*)d_ws;
  size_t off = 0;
  const _Float16* wptr[20];
  for (int j = 0; j < 20; ++j) {
    J.src[j] = (const float*)d_in[widx[j]];
    J.dst[j] = wsp + off;
    J.n[j]   = in_sizes[widx[j]];
    wptr[j]  = wsp + off;
    off += in_sizes[widx[j]];
  }
  cvt_kernel<<<dim3(32, 20), dim3(256), 0, stream>>>(J);

  WB W;
  W.g1_Wvh = wptr[0];  W.g1_Ws = wptr[1];  W.g1_Wvo = wptr[2];  W.g1_Wg = wptr[3];  W.g1_Wd = wptr[4];
  W.g2_Wvh = wptr[5];  W.g2_Ws = wptr[6];  W.g2_Wvo = wptr[7];  W.g2_Wg = wptr[8];
  W.a1_Wvh = wptr[9];  W.a1_Ws = wptr[10]; W.a1_Wvo = wptr[11]; W.a1_Wg = wptr[12]; W.a1_Wd = wptr[13];
  W.a2_Wvh = wptr[14]; W.a2_Ws = wptr[15]; W.a2_Wvo = wptr[16]; W.a2_Wg = wptr[17]; W.a2_Wd = wptr[18];
  W.f_Wvh  = wptr[19];
  W.g1_bg = (const float*)d_in[8];
  W.g2_bg = (const float*)d_in[14];
  W.a1_bg = (const float*)d_in[19];
  W.a2_bg = (const float*)d_in[25];
  W.f_Ws  = (const float*)d_in[28];

  const int blocks = (F + E - 1) / E;
  pe_kernel<<<dim3(blocks), dim3(TPB), 0, stream>>>(
      h_sca, h_vec, pos_compose, pos, W, idx_focal, (float*)d_out, F);
}